// Round 5
// baseline (231.557 us; speedup 1.0000x reference)
//
#include <hip/hip_runtime.h>
#include <hip/hip_bf16.h>

// Problem constants: B=4,S=2048 -> T=8192 tokens, H=1024, E=8, TOP_K=2
#define H 1024
#define NEXP 8
#define T_TOK 8192
#define CAP 8192
#define TM 128
#define TN 128
#define CNTSTRIDE 32

typedef __bf16 bf16x8 __attribute__((ext_vector_type(8)));
typedef __bf16 bf16x4 __attribute__((ext_vector_type(4)));
typedef float f32x4 __attribute__((ext_vector_type(4)));

__device__ __forceinline__ void async16(void* lds, const void* g) {
    __builtin_amdgcn_global_load_lds(
        (const __attribute__((address_space(1))) void*)g,
        (__attribute__((address_space(3))) void*)lds, 16, 0, 0);
}

// ---------------- transpose: We (E,h,d) fp32 -> WeT (E,d,h) bf16, 64x64 tiles ----------------
__global__ __launch_bounds__(256) void moe_transpose(
    const float* __restrict__ We, __bf16* __restrict__ WeT) {
    __shared__ __align__(16) float t[64][65];   // stride 65: 2-way alias only (free, m136)
    const int tid = threadIdx.x;
    const int tt = blockIdx.x;
    const int e  = tt >> 8;
    const int d0 = ((tt >> 4) & 15) * 64;
    const int h0 = (tt & 15) * 64;
    const int tx = tid & 15;
    const int ty = tid >> 4;
    const float* src = We + ((size_t)e << 20);
    __bf16* dst = WeT + ((size_t)e << 20);
#pragma unroll
    for (int p = 0; p < 4; ++p) {
        const int row = p * 16 + ty;
        const float4 v = *(const float4*)(src + (size_t)(h0 + row) * H + d0 + tx * 4);
        t[row][tx * 4 + 0] = v.x; t[row][tx * 4 + 1] = v.y;
        t[row][tx * 4 + 2] = v.z; t[row][tx * 4 + 3] = v.w;
    }
    __syncthreads();
    // 512 bf16x8 chunks (drow, seg), 2/thread. LDS bank check: word = (seg*8+i)*65+drow;
    // across 64 lanes -> 2-way alias only.
#pragma unroll
    for (int qq = 0; qq < 2; ++qq) {
        const int q = tid + qq * 256;
        const int drow = q >> 3;
        const int seg  = q & 7;
        bf16x8 o;
#pragma unroll
        for (int i = 0; i < 8; ++i) o[i] = (__bf16)t[seg * 8 + i][drow];
        *(bf16x8*)(dst + (size_t)(d0 + drow) * H + h0 + seg * 8) = o;
    }
}

// ---------------- route: logits, top-2, gates, compaction; fused x -> bf16 cast -------------
// R10 structure (upfront independent loads). R11: writes ltok+lgate only (tsel/tgate gone
// with the combine kernel).
__global__ __launch_bounds__(256) void moe_route(
    const float* __restrict__ x, const float* __restrict__ Wg,
    __bf16* __restrict__ Xb, int* __restrict__ cnt,
    int* __restrict__ ltok, float* __restrict__ lgate) {
    __shared__ int   sE[32];
    __shared__ float sG[32];
    __shared__ int   lcnt[NEXP], lbase[NEXP], lslot[32];
    const int tid  = threadIdx.x;
    const int lane = tid & 63;
    const int wave = tid >> 6;
    const int base = blockIdx.x * 16;

    // ---- upfront loads: 16 independent float4s (4 tokens x 4 chunks) ----
    float4 xv[4][4];
#pragma unroll
    for (int tk = 0; tk < 4; ++tk) {
        const float* xr = x + (size_t)(base + wave * 4 + tk) * H;
#pragma unroll
        for (int c = 0; c < 4; ++c)
            xv[tk][c] = *(const float4*)(xr + c * 256 + lane * 4);
    }

    float a[4][NEXP];
#pragma unroll
    for (int tk = 0; tk < 4; ++tk)
#pragma unroll
        for (int e = 0; e < NEXP; ++e) a[tk][e] = 0.f;

#pragma unroll
    for (int c = 0; c < 4; ++c) {
        const float* wgp = Wg + (size_t)(c * 256 + lane * 4) * NEXP;
        float4 w[8];
#pragma unroll
        for (int r = 0; r < 8; ++r) w[r] = *(const float4*)(wgp + r * 4);
#pragma unroll
        for (int tk = 0; tk < 4; ++tk) {
            const float xc[4] = {xv[tk][c].x, xv[tk][c].y, xv[tk][c].z, xv[tk][c].w};
#pragma unroll
            for (int i = 0; i < 4; ++i) {
                a[tk][0] += xc[i] * w[i * 2].x;     a[tk][1] += xc[i] * w[i * 2].y;
                a[tk][2] += xc[i] * w[i * 2].z;     a[tk][3] += xc[i] * w[i * 2].w;
                a[tk][4] += xc[i] * w[i * 2 + 1].x; a[tk][5] += xc[i] * w[i * 2 + 1].y;
                a[tk][6] += xc[i] * w[i * 2 + 1].z; a[tk][7] += xc[i] * w[i * 2 + 1].w;
            }
        }
    }

    // ---- fused bf16 cast of x (fire-and-forget stores) ----
#pragma unroll
    for (int tk = 0; tk < 4; ++tk) {
        __bf16* xbr = Xb + (size_t)(base + wave * 4 + tk) * H;
#pragma unroll
        for (int c = 0; c < 4; ++c) {
            bf16x4 xo;
            xo[0] = (__bf16)xv[tk][c].x; xo[1] = (__bf16)xv[tk][c].y;
            xo[2] = (__bf16)xv[tk][c].z; xo[3] = (__bf16)xv[tk][c].w;
            *(bf16x4*)(xbr + c * 256 + lane * 4) = xo;
        }
    }

    // ---- reduce + top-2 + gates per token ----
#pragma unroll
    for (int tk = 0; tk < 4; ++tk) {
        const int tl = wave * 4 + tk;
#pragma unroll
        for (int e = 0; e < NEXP; ++e) {
#pragma unroll
            for (int off = 32; off > 0; off >>= 1)
                a[tk][e] += __shfl_xor(a[tk][e], off, 64);
        }
        int i0 = 0;
#pragma unroll
        for (int e = 1; e < NEXP; ++e) if (a[tk][e] > a[tk][i0]) i0 = e;  // jax tie-break: lowest idx
        int i1 = (i0 == 0) ? 1 : 0;
#pragma unroll
        for (int e = 0; e < NEXP; ++e) if (e != i0 && a[tk][e] > a[tk][i1]) i1 = e;
        const float ex = __expf(a[tk][i1] - a[tk][i0]);
        const float g0 = 1.f / (1.f + ex);
        const float g1 = ex / (1.f + ex);
        if (lane == 0) {
            sE[tl * 2] = i0; sE[tl * 2 + 1] = i1;
            sG[tl * 2] = g0; sG[tl * 2 + 1] = g1;
        }
    }
    if (tid < NEXP) lcnt[tid] = 0;
    __syncthreads();
    if (tid < 32) lslot[tid] = atomicAdd(&lcnt[sE[tid]], 1);
    __syncthreads();
    if (tid < NEXP) lbase[tid] = lcnt[tid] ? atomicAdd(&cnt[tid * CNTSTRIDE], lcnt[tid]) : 0;
    __syncthreads();
    if (tid < 32) {
        const int e = sE[tid];
        const int s = lbase[e] + lslot[tid];
        ltok[e * CAP + s]  = base + (tid >> 1);
        lgate[e * CAP + s] = sG[tid];
    }
}

// ---------------- grouped GEMM + fused combine: 128x128 tile, BK=64, bf16 MFMA --------------
// R6 main loop (proven ~55us / ~620 TF; 33KB LDS -> ~4 blocks/CU inter-block overlap, m114).
// R11: epilogue writes gate*(acc+be) DIRECTLY into out via fp32 atomicAdd. Each out element
// receives exactly 2 contributions (one per selected expert); fp32 add is commutative so the
// result is bit-deterministic regardless of block order. Removes Eout + the combine kernel.
// XCD-pinned swizzle: blockIdx&7 = expert keeps each expert's 2MB B-panel L2-resident.
__global__ __launch_bounds__(256) void moe_gemm(
    const __bf16* __restrict__ Xb, const __bf16* __restrict__ WeT,
    const float* __restrict__ be, const int* __restrict__ cnt,
    const int* __restrict__ ltok, const float* __restrict__ lgate,
    float* __restrict__ out) {
    const int e  = blockIdx.x & 7;
    const int nt = (blockIdx.x >> 3) & 7;
    const int mt = blockIdx.x >> 6;
    const int ne = cnt[e * CNTSTRIDE];
    const int m0 = mt * TM;
    if (m0 >= ne) return;
    const int n0 = nt * TN;

    __shared__ __align__(16) __bf16 smem[4 * 4096];  // Al|Al2|Bl|Bl2
    __bf16* Al  = smem;
    __bf16* Al2 = smem + 4096;
    __bf16* Bl  = smem + 8192;
    __bf16* Bl2 = smem + 12288;
    __shared__ int   tokL[TM];
    __shared__ float gateL[TM];

    const int tid = threadIdx.x;
    const int lane = tid & 63;
    const int wave = tid >> 6;

    if (tid < TM) {
        const int gi = m0 + tid;
        tokL[tid]  = (gi < ne) ? ltok[e * CAP + gi] : 0;
        gateL[tid] = (gi < ne) ? lgate[e * CAP + gi] : 0.f;
    }
    __syncthreads();

    const __bf16* Bt = WeT + ((size_t)e << 20);
    const int qr = lane >> 4;
    const int rr = lane & 15;
    const int wr = (wave >> 1) * 64;
    const int wc = (wave & 1) * 64;

    f32x4 acc[4][4];
    const f32x4 z = {0.f, 0.f, 0.f, 0.f};
#pragma unroll
    for (int i = 0; i < 4; ++i)
#pragma unroll
        for (int j = 0; j < 4; ++j) acc[i][j] = z;

    const int c0 = tid, c1 = tid + 256;
    const int ar0 = c0 >> 2, ak0 = (((c0 & 3) ^ ((c0 >> 3) & 3)) * 8);
    const int ar1 = c1 >> 2, ak1 = (((c1 & 3) ^ ((c1 >> 3) & 3)) * 8);
    const size_t arow0 = (size_t)tokL[ar0] * H;
    const size_t arow1 = (size_t)tokL[ar1] * H;
    const size_t brow0 = (size_t)(n0 + ar0) * H;
    const size_t brow1 = (size_t)(n0 + ar1) * H;

    for (int k0 = 0; k0 < H; k0 += 64) {
        async16(&Al [c0 * 8], Xb + arow0 + k0 + ak0);
        async16(&Al [c1 * 8], Xb + arow1 + k0 + ak1);
        async16(&Al2[c0 * 8], Xb + arow0 + k0 + 32 + ak0);
        async16(&Al2[c1 * 8], Xb + arow1 + k0 + 32 + ak1);
        async16(&Bl [c0 * 8], Bt + brow0 + k0 + ak0);
        async16(&Bl [c1 * 8], Bt + brow1 + k0 + ak1);
        async16(&Bl2[c0 * 8], Bt + brow0 + k0 + 32 + ak0);
        async16(&Bl2[c1 * 8], Bt + brow1 + k0 + 32 + ak1);
        __syncthreads();
        {
            bf16x8 af[4], bfr[4];
#pragma unroll
            for (int i = 0; i < 4; ++i) {
                const int ra = wr + i * 16 + rr;
                af[i] = *(const bf16x8*)&Al[ra * 32 + ((qr ^ ((ra >> 1) & 3)) * 8)];
            }
#pragma unroll
            for (int j = 0; j < 4; ++j) {
                const int rb = wc + j * 16 + rr;
                bfr[j] = *(const bf16x8*)&Bl[rb * 32 + ((qr ^ ((rb >> 1) & 3)) * 8)];
            }
#pragma unroll
            for (int i = 0; i < 4; ++i)
#pragma unroll
                for (int j = 0; j < 4; ++j)
                    acc[i][j] = __builtin_amdgcn_mfma_f32_16x16x32_bf16(af[i], bfr[j], acc[i][j], 0, 0, 0);
        }
        {
            bf16x8 af[4], bfr[4];
#pragma unroll
            for (int i = 0; i < 4; ++i) {
                const int ra = wr + i * 16 + rr;
                af[i] = *(const bf16x8*)&Al2[ra * 32 + ((qr ^ ((ra >> 1) & 3)) * 8)];
            }
#pragma unroll
            for (int j = 0; j < 4; ++j) {
                const int rb = wc + j * 16 + rr;
                bfr[j] = *(const bf16x8*)&Bl2[rb * 32 + ((qr ^ ((rb >> 1) & 3)) * 8)];
            }
#pragma unroll
            for (int i = 0; i < 4; ++i)
#pragma unroll
                for (int j = 0; j < 4; ++j)
                    acc[i][j] = __builtin_amdgcn_mfma_f32_16x16x32_bf16(af[i], bfr[j], acc[i][j], 0, 0, 0);
        }
        __syncthreads();
    }

    float bev[4];
#pragma unroll
    for (int j = 0; j < 4; ++j) bev[j] = be[e * H + n0 + wc + j * 16 + rr];

    // ---- fused-combine epilogue: out[tok] += gate * (acc + be), fp32 atomics -----------
    // Per instr: 64 lanes hit 4 rows x 16 consecutive floats (4 x 64B segments). Each out
    // element receives exactly 2 atomic adds total -> no contention, deterministic sum.
#pragma unroll
    for (int i = 0; i < 4; ++i) {
#pragma unroll
        for (int reg = 0; reg < 4; ++reg) {
            const int row = wr + i * 16 + qr * 4 + reg;  // C/D: col=lane&15, row=quad*4+reg
            if (m0 + row < ne) {
                const float g = gateL[row];
                float* orow = out + (size_t)tokL[row] * H + n0 + wc;
#pragma unroll
                for (int j = 0; j < 4; ++j)
                    atomicAdd(orow + j * 16 + rr, g * (acc[i][j][reg] + bev[j]));
            }
        }
    }
}

extern "C" void kernel_launch(void* const* d_in, const int* in_sizes, int n_in,
                              void* d_out, int out_size, void* d_ws, size_t ws_size,
                              hipStream_t stream) {
    const float* x  = (const float*)d_in[0];
    const float* Wg = (const float*)d_in[1];
    const float* We = (const float*)d_in[2];
    const float* be = (const float*)d_in[3];
    float* out = (float*)d_out;

    char* ws = (char*)d_ws;
    __bf16* Xb   = (__bf16*)ws;
    __bf16* WeT  = (__bf16*)(ws + ((size_t)16 << 20));
    char*   meta = ws + ((size_t)64 << 20);
    int*    cnt  = (int*)meta;
    int*    ltok = (int*)(meta + 1024);
    float*  lgat = (float*)(meta + 1024 + (size_t)NEXP * CAP * 4);

    hipMemsetAsync(cnt, 0, NEXP * CNTSTRIDE * sizeof(int), stream);
    hipMemsetAsync(out, 0, (size_t)T_TOK * H * sizeof(float), stream);

    moe_transpose<<<2048, 256, 0, stream>>>(We, WeT);
    moe_route<<<512, 256, 0, stream>>>(x, Wg, Xb, cnt, ltok, lgat);
    moe_gemm<<<8 * 8 * (T_TOK / TM), 256, 0, stream>>>(Xb, WeT, be, cnt, ltok, lgat, out);
}

// Round 6
// 213.700 us; speedup vs baseline: 1.0836x; 1.0836x over previous
//
#include <hip/hip_runtime.h>
#include <hip/hip_bf16.h>

// Problem constants: B=4,S=2048 -> T=8192 tokens, H=1024, E=8, TOP_K=2
#define H 1024
#define NEXP 8
#define T_TOK 8192
#define CAP 8192
#define TM 128
#define TN 128
#define CNTSTRIDE 32

typedef __bf16 bf16x8 __attribute__((ext_vector_type(8)));
typedef __bf16 bf16x4 __attribute__((ext_vector_type(4)));
typedef float f32x4 __attribute__((ext_vector_type(4)));

__device__ __forceinline__ void async16(void* lds, const void* g) {
    __builtin_amdgcn_global_load_lds(
        (const __attribute__((address_space(1))) void*)g,
        (__attribute__((address_space(3))) void*)lds, 16, 0, 0);
}

// ---------------- transpose: We (E,h,d) fp32 -> WeT (E,d,h) bf16, 64x64 tiles ----------------
// R12: block 0 also zeroes cnt (replaces the hipMemsetAsync dispatch; transpose fully
// precedes route by stream order, so route's atomics always see zeroed counters).
__global__ __launch_bounds__(256) void moe_transpose(
    const float* __restrict__ We, __bf16* __restrict__ WeT, int* __restrict__ cnt) {
    __shared__ __align__(16) float t[64][65];   // stride 65: 2-way alias only (free, m136)
    const int tid = threadIdx.x;
    if (blockIdx.x == 0 && tid < NEXP) cnt[tid * CNTSTRIDE] = 0;
    const int tt = blockIdx.x;
    const int e  = tt >> 8;
    const int d0 = ((tt >> 4) & 15) * 64;
    const int h0 = (tt & 15) * 64;
    const int tx = tid & 15;
    const int ty = tid >> 4;
    const float* src = We + ((size_t)e << 20);
    __bf16* dst = WeT + ((size_t)e << 20);
#pragma unroll
    for (int p = 0; p < 4; ++p) {
        const int row = p * 16 + ty;
        const float4 v = *(const float4*)(src + (size_t)(h0 + row) * H + d0 + tx * 4);
        t[row][tx * 4 + 0] = v.x; t[row][tx * 4 + 1] = v.y;
        t[row][tx * 4 + 2] = v.z; t[row][tx * 4 + 3] = v.w;
    }
    __syncthreads();
    // 512 bf16x8 chunks (drow, seg), 2/thread. LDS bank check: word = (seg*8+i)*65+drow;
    // across 64 lanes -> 2-way alias only.
#pragma unroll
    for (int qq = 0; qq < 2; ++qq) {
        const int q = tid + qq * 256;
        const int drow = q >> 3;
        const int seg  = q & 7;
        bf16x8 o;
#pragma unroll
        for (int i = 0; i < 8; ++i) o[i] = (__bf16)t[seg * 8 + i][drow];
        *(bf16x8*)(dst + (size_t)(d0 + drow) * H + h0 + seg * 8) = o;
    }
}

// ---------------- route: logits, top-2, gates, compaction; fused x -> bf16 cast -------------
// R12: 1024 blocks x 8 tokens (2 tokens/wave) -> 4 blocks/CU (~16 waves/CU at ~100 VGPR),
// fixing the 512-block (2 blocks/CU) occupancy limiter of R10. Upfront independent loads
// per wave (8 float4); Wg slice loaded once per c and reused across the wave's 2 tokens.
// Per-block LDS aggregation keeps global atomics at 8/block (8K total).
__global__ __launch_bounds__(256) void moe_route(
    const float* __restrict__ x, const float* __restrict__ Wg,
    __bf16* __restrict__ Xb, int* __restrict__ cnt,
    int* __restrict__ ltok,
    int* __restrict__ tsel, float* __restrict__ tgate) {
    __shared__ int   sE[16];
    __shared__ float sG[16];
    __shared__ int   lcnt[NEXP], lbase[NEXP], lslot[16];
    const int tid  = threadIdx.x;
    const int lane = tid & 63;
    const int wave = tid >> 6;
    const int base = blockIdx.x * 8;

    // ---- upfront loads: 8 independent float4s (2 tokens x 4 chunks) ----
    float4 xv[2][4];
#pragma unroll
    for (int tk = 0; tk < 2; ++tk) {
        const float* xr = x + (size_t)(base + wave * 2 + tk) * H;
#pragma unroll
        for (int c = 0; c < 4; ++c)
            xv[tk][c] = *(const float4*)(xr + c * 256 + lane * 4);
    }

    float a[2][NEXP];
#pragma unroll
    for (int tk = 0; tk < 2; ++tk)
#pragma unroll
        for (int e = 0; e < NEXP; ++e) a[tk][e] = 0.f;

#pragma unroll
    for (int c = 0; c < 4; ++c) {
        const float* wgp = Wg + (size_t)(c * 256 + lane * 4) * NEXP;
        float4 w[8];
#pragma unroll
        for (int r = 0; r < 8; ++r) w[r] = *(const float4*)(wgp + r * 4);
#pragma unroll
        for (int tk = 0; tk < 2; ++tk) {
            const float xc[4] = {xv[tk][c].x, xv[tk][c].y, xv[tk][c].z, xv[tk][c].w};
#pragma unroll
            for (int i = 0; i < 4; ++i) {
                a[tk][0] += xc[i] * w[i * 2].x;     a[tk][1] += xc[i] * w[i * 2].y;
                a[tk][2] += xc[i] * w[i * 2].z;     a[tk][3] += xc[i] * w[i * 2].w;
                a[tk][4] += xc[i] * w[i * 2 + 1].x; a[tk][5] += xc[i] * w[i * 2 + 1].y;
                a[tk][6] += xc[i] * w[i * 2 + 1].z; a[tk][7] += xc[i] * w[i * 2 + 1].w;
            }
        }
    }

    // ---- fused bf16 cast of x (fire-and-forget stores) ----
#pragma unroll
    for (int tk = 0; tk < 2; ++tk) {
        __bf16* xbr = Xb + (size_t)(base + wave * 2 + tk) * H;
#pragma unroll
        for (int c = 0; c < 4; ++c) {
            bf16x4 xo;
            xo[0] = (__bf16)xv[tk][c].x; xo[1] = (__bf16)xv[tk][c].y;
            xo[2] = (__bf16)xv[tk][c].z; xo[3] = (__bf16)xv[tk][c].w;
            *(bf16x4*)(xbr + c * 256 + lane * 4) = xo;
        }
    }

    // ---- reduce + top-2 + gates per token ----
#pragma unroll
    for (int tk = 0; tk < 2; ++tk) {
        const int tl = wave * 2 + tk;
#pragma unroll
        for (int e = 0; e < NEXP; ++e) {
#pragma unroll
            for (int off = 32; off > 0; off >>= 1)
                a[tk][e] += __shfl_xor(a[tk][e], off, 64);
        }
        int i0 = 0;
#pragma unroll
        for (int e = 1; e < NEXP; ++e) if (a[tk][e] > a[tk][i0]) i0 = e;  // jax tie-break: lowest idx
        int i1 = (i0 == 0) ? 1 : 0;
#pragma unroll
        for (int e = 0; e < NEXP; ++e) if (e != i0 && a[tk][e] > a[tk][i1]) i1 = e;
        const float ex = __expf(a[tk][i1] - a[tk][i0]);
        const float g0 = 1.f / (1.f + ex);
        const float g1 = ex / (1.f + ex);
        if (lane == 0) {
            sE[tl * 2] = i0; sE[tl * 2 + 1] = i1;
            sG[tl * 2] = g0; sG[tl * 2 + 1] = g1;
        }
    }
    if (tid < NEXP) lcnt[tid] = 0;
    __syncthreads();
    if (tid < 16) lslot[tid] = atomicAdd(&lcnt[sE[tid]], 1);
    __syncthreads();
    if (tid < NEXP) lbase[tid] = lcnt[tid] ? atomicAdd(&cnt[tid * CNTSTRIDE], lcnt[tid]) : 0;
    __syncthreads();
    if (tid < 16) {
        const int e = sE[tid];
        const int s = lbase[e] + lslot[tid];
        const int t = base + (tid >> 1);
        ltok[e * CAP + s] = t;
        tsel[t * 2 + (tid & 1)]  = e * CAP + s;
        tgate[t * 2 + (tid & 1)] = sG[tid];
    }
}

// ---------------- grouped GEMM: 128x128 tile, BK=64 (two BK=32 panels), bf16 MFMA ----------------
// R6/R10 structure (proven ~55us / ~620 TF): 33KB LDS -> ~4 blocks/CU; inter-block overlap
// (m114) beats both the 1-block/CU hand pipeline (R7, 78us) and the atomic fused-combine
// epilogue (R11, 91us). XCD-pinned swizzle: blockIdx&7 = expert (L2-resident B-panel).
__global__ __launch_bounds__(256) void moe_gemm(
    const __bf16* __restrict__ Xb, const __bf16* __restrict__ WeT,
    const float* __restrict__ be, const int* __restrict__ cnt,
    const int* __restrict__ ltok,
    __bf16* __restrict__ Eout) {
    const int e  = blockIdx.x & 7;
    const int nt = (blockIdx.x >> 3) & 7;
    const int mt = blockIdx.x >> 6;
    const int ne = cnt[e * CNTSTRIDE];
    const int m0 = mt * TM;
    if (m0 >= ne) return;
    const int n0 = nt * TN;
    int off = 0;
    for (int i2 = 0; i2 < e; ++i2) off += cnt[i2 * CNTSTRIDE];

    __shared__ __align__(16) __bf16 smem[4 * 4096];  // Al|Al2|Bl|Bl2; epilogue: 4 x (64x64)
    __bf16* Al  = smem;
    __bf16* Al2 = smem + 4096;
    __bf16* Bl  = smem + 8192;
    __bf16* Bl2 = smem + 12288;
    __shared__ int tokL[TM];

    const int tid = threadIdx.x;
    const int lane = tid & 63;
    const int wave = tid >> 6;

    if (tid < TM) {
        const int gi = m0 + tid;
        tokL[tid] = (gi < ne) ? ltok[e * CAP + gi] : 0;
    }
    __syncthreads();

    const __bf16* Bt = WeT + ((size_t)e << 20);
    const int qr = lane >> 4;
    const int rr = lane & 15;
    const int wr = (wave >> 1) * 64;
    const int wc = (wave & 1) * 64;

    f32x4 acc[4][4];
    const f32x4 z = {0.f, 0.f, 0.f, 0.f};
#pragma unroll
    for (int i = 0; i < 4; ++i)
#pragma unroll
        for (int j = 0; j < 4; ++j) acc[i][j] = z;

    const int c0 = tid, c1 = tid + 256;
    const int ar0 = c0 >> 2, ak0 = (((c0 & 3) ^ ((c0 >> 3) & 3)) * 8);
    const int ar1 = c1 >> 2, ak1 = (((c1 & 3) ^ ((c1 >> 3) & 3)) * 8);
    const size_t arow0 = (size_t)tokL[ar0] * H;
    const size_t arow1 = (size_t)tokL[ar1] * H;
    const size_t brow0 = (size_t)(n0 + ar0) * H;
    const size_t brow1 = (size_t)(n0 + ar1) * H;

    for (int k0 = 0; k0 < H; k0 += 64) {
        async16(&Al [c0 * 8], Xb + arow0 + k0 + ak0);
        async16(&Al [c1 * 8], Xb + arow1 + k0 + ak1);
        async16(&Al2[c0 * 8], Xb + arow0 + k0 + 32 + ak0);
        async16(&Al2[c1 * 8], Xb + arow1 + k0 + 32 + ak1);
        async16(&Bl [c0 * 8], Bt + brow0 + k0 + ak0);
        async16(&Bl [c1 * 8], Bt + brow1 + k0 + ak1);
        async16(&Bl2[c0 * 8], Bt + brow0 + k0 + 32 + ak0);
        async16(&Bl2[c1 * 8], Bt + brow1 + k0 + 32 + ak1);
        __syncthreads();
        {
            bf16x8 af[4], bfr[4];
#pragma unroll
            for (int i = 0; i < 4; ++i) {
                const int ra = wr + i * 16 + rr;
                af[i] = *(const bf16x8*)&Al[ra * 32 + ((qr ^ ((ra >> 1) & 3)) * 8)];
            }
#pragma unroll
            for (int j = 0; j < 4; ++j) {
                const int rb = wc + j * 16 + rr;
                bfr[j] = *(const bf16x8*)&Bl[rb * 32 + ((qr ^ ((rb >> 1) & 3)) * 8)];
            }
#pragma unroll
            for (int i = 0; i < 4; ++i)
#pragma unroll
                for (int j = 0; j < 4; ++j)
                    acc[i][j] = __builtin_amdgcn_mfma_f32_16x16x32_bf16(af[i], bfr[j], acc[i][j], 0, 0, 0);
        }
        {
            bf16x8 af[4], bfr[4];
#pragma unroll
            for (int i = 0; i < 4; ++i) {
                const int ra = wr + i * 16 + rr;
                af[i] = *(const bf16x8*)&Al2[ra * 32 + ((qr ^ ((ra >> 1) & 3)) * 8)];
            }
#pragma unroll
            for (int j = 0; j < 4; ++j) {
                const int rb = wc + j * 16 + rr;
                bfr[j] = *(const bf16x8*)&Bl2[rb * 32 + ((qr ^ ((rb >> 1) & 3)) * 8)];
            }
#pragma unroll
            for (int i = 0; i < 4; ++i)
#pragma unroll
                for (int j = 0; j < 4; ++j)
                    acc[i][j] = __builtin_amdgcn_mfma_f32_16x16x32_bf16(af[i], bfr[j], acc[i][j], 0, 0, 0);
        }
        __syncthreads();   // also protects smem reuse by the epilogue on the last iter
    }

    float bev[4];
#pragma unroll
    for (int j = 0; j < 4; ++j) bev[j] = be[e * H + n0 + wc + j * 16 + rr];

    // ---- epilogue: per-wave 64x64 LDS stage (XOR col swizzle), then full-line bf16x8 stores ----
    __bf16* Cw = smem + wave * 4096;
#pragma unroll
    for (int i = 0; i < 4; ++i) {
#pragma unroll
        for (int reg = 0; reg < 4; ++reg) {
            const int row = i * 16 + qr * 4 + reg;      // C/D layout: col=lane&15, row=quad*4+reg
            const int key = (row & 7) * 8;
#pragma unroll
            for (int j = 0; j < 4; ++j) {
                const int c = j * 16 + rr;
                Cw[row * 64 + (c ^ key)] = (__bf16)(acc[i][j][reg] + bev[j]);
            }
        }
    }
    const int lrr = lane & 7, lrg = lane >> 3;
#pragma unroll
    for (int p = 0; p < 8; ++p) {
        const int row = p * 8 + lrg;
        const int rglob = m0 + wr + row;
        if (rglob < ne) {
            const int idx8 = ((lrr ^ (row & 7)) * 8);
            const bf16x8 v = *(const bf16x8*)&Cw[row * 64 + idx8];
            *(bf16x8*)(Eout + (size_t)(off + rglob) * H + n0 + wc + lrr * 8) = v;
        }
    }
}

// ---------------- combine: wave per token, out[t] = g0*row0 + g1*row1 (~12us, near roofline) ----
__global__ __launch_bounds__(256) void moe_combine(
    const __bf16* __restrict__ Eout, const int* __restrict__ cnt,
    const int* __restrict__ tsel, const float* __restrict__ tgate,
    float* __restrict__ out) {
    __shared__ int offs[NEXP];
    if (threadIdx.x < NEXP) {
        int o = 0;
        for (int i = 0; i < (int)threadIdx.x; ++i) o += cnt[i * CNTSTRIDE];
        offs[threadIdx.x] = o;
    }
    __syncthreads();
    const int wave = threadIdx.x >> 6, lane = threadIdx.x & 63;
    const int t = blockIdx.x * 4 + wave;
    const int sel0 = tsel[t * 2],  sel1 = tsel[t * 2 + 1];
    const float g0 = tgate[t * 2], g1  = tgate[t * 2 + 1];
    const int e0 = sel0 >> 13, s0 = sel0 & (CAP - 1);
    const int e1 = sel1 >> 13, s1 = sel1 & (CAP - 1);
    const __bf16* r0 = Eout + (size_t)(offs[e0] + s0) * H;
    const __bf16* r1 = Eout + (size_t)(offs[e1] + s1) * H;
    float* orow = out + (size_t)t * H;
#pragma unroll
    for (int c = 0; c < 2; ++c) {
        const int d = c * 512 + lane * 8;
        const bf16x8 a = *(const bf16x8*)(r0 + d);
        const bf16x8 b = *(const bf16x8*)(r1 + d);
        float4 o0, o1;
        o0.x = g0 * (float)a[0] + g1 * (float)b[0];
        o0.y = g0 * (float)a[1] + g1 * (float)b[1];
        o0.z = g0 * (float)a[2] + g1 * (float)b[2];
        o0.w = g0 * (float)a[3] + g1 * (float)b[3];
        o1.x = g0 * (float)a[4] + g1 * (float)b[4];
        o1.y = g0 * (float)a[5] + g1 * (float)b[5];
        o1.z = g0 * (float)a[6] + g1 * (float)b[6];
        o1.w = g0 * (float)a[7] + g1 * (float)b[7];
        *(float4*)(orow + d)     = o0;
        *(float4*)(orow + d + 4) = o1;
    }
}

extern "C" void kernel_launch(void* const* d_in, const int* in_sizes, int n_in,
                              void* d_out, int out_size, void* d_ws, size_t ws_size,
                              hipStream_t stream) {
    const float* x  = (const float*)d_in[0];
    const float* Wg = (const float*)d_in[1];
    const float* We = (const float*)d_in[2];
    const float* be = (const float*)d_in[3];
    float* out = (float*)d_out;

    char* ws = (char*)d_ws;
    __bf16* Xb   = (__bf16*)ws;
    __bf16* WeT  = (__bf16*)(ws + ((size_t)16 << 20));
    __bf16* Eout = (__bf16*)(ws + ((size_t)32 << 20));
    char*   meta = ws + ((size_t)64 << 20);
    int*    cnt  = (int*)meta;
    int*    ltok = (int*)(meta + 1024);
    int*    tsel = (int*)(meta + 1024 + (size_t)NEXP * CAP * 8);
    float*  tgat = (float*)(meta + 1024 + (size_t)NEXP * CAP * 8 + (size_t)T_TOK * 8);

    moe_transpose<<<2048, 256, 0, stream>>>(We, WeT, cnt);
    moe_route<<<1024, 256, 0, stream>>>(x, Wg, Xb, cnt, ltok, tsel, tgat);
    moe_gemm<<<8 * 8 * (T_TOK / TM), 256, 0, stream>>>(Xb, WeT, be, cnt, ltok, Eout);
    moe_combine<<<T_TOK / 4, 256, 0, stream>>>(Eout, cnt, tsel, tgat, out);
}

// Round 7
// 210.945 us; speedup vs baseline: 1.0977x; 1.0131x over previous
//
#include <hip/hip_runtime.h>
#include <hip/hip_bf16.h>

// Problem constants: B=4,S=2048 -> T=8192 tokens, H=1024, E=8, TOP_K=2
#define H 1024
#define NEXP 8
#define T_TOK 8192
#define CAP 8192
#define TM 128
#define TN 128
#define CNTSTRIDE 32

typedef __bf16 bf16x8 __attribute__((ext_vector_type(8)));
typedef __bf16 bf16x4 __attribute__((ext_vector_type(4)));
typedef float f32x4 __attribute__((ext_vector_type(4)));

__device__ __forceinline__ void async16(void* lds, const void* g) {
    __builtin_amdgcn_global_load_lds(
        (const __attribute__((address_space(1))) void*)g,
        (__attribute__((address_space(3))) void*)lds, 16, 0, 0);
}

// ---------------- transpose: We (E,h,d) fp32 -> WeT (E,d,h) bf16, 64x64 tiles ----------------
// Block 0 also zeroes cnt (replaces the hipMemsetAsync dispatch; transpose fully precedes
// route by stream order, so route's atomics always see zeroed counters).
__global__ __launch_bounds__(256) void moe_transpose(
    const float* __restrict__ We, __bf16* __restrict__ WeT, int* __restrict__ cnt) {
    __shared__ __align__(16) float t[64][65];   // stride 65: 2-way alias only (free, m136)
    const int tid = threadIdx.x;
    if (blockIdx.x == 0 && tid < NEXP) cnt[tid * CNTSTRIDE] = 0;
    const int tt = blockIdx.x;
    const int e  = tt >> 8;
    const int d0 = ((tt >> 4) & 15) * 64;
    const int h0 = (tt & 15) * 64;
    const int tx = tid & 15;
    const int ty = tid >> 4;
    const float* src = We + ((size_t)e << 20);
    __bf16* dst = WeT + ((size_t)e << 20);
#pragma unroll
    for (int p = 0; p < 4; ++p) {
        const int row = p * 16 + ty;
        const float4 v = *(const float4*)(src + (size_t)(h0 + row) * H + d0 + tx * 4);
        t[row][tx * 4 + 0] = v.x; t[row][tx * 4 + 1] = v.y;
        t[row][tx * 4 + 2] = v.z; t[row][tx * 4 + 3] = v.w;
    }
    __syncthreads();
    // 512 bf16x8 chunks (drow, seg), 2/thread. LDS bank check: word = (seg*8+i)*65+drow;
    // across 64 lanes -> 2-way alias only.
#pragma unroll
    for (int qq = 0; qq < 2; ++qq) {
        const int q = tid + qq * 256;
        const int drow = q >> 3;
        const int seg  = q & 7;
        bf16x8 o;
#pragma unroll
        for (int i = 0; i < 8; ++i) o[i] = (__bf16)t[seg * 8 + i][drow];
        *(bf16x8*)(dst + (size_t)(d0 + drow) * H + h0 + seg * 8) = o;
    }
}

// ---------------- route: logits, top-2, gates, compaction; fused x -> bf16 cast -------------
// R13 rebuild. Evidence (R12 counters): VALUBusy 4.5%, 3.6M LDS-conflict cycles, occupancy
// 27% -> latency-bound on (a) serialized load chains (VGPR=40 couldn't hold the upfront
// loads), (b) 96 dependent shfl_xor/wave (8 experts x 6-deep x 2 tok, ~9 conflict-cyc each).
// Fix: 1 token/wave, 2048 blocks; ALL 36 loads (4 x-float4 + 32 Wg-float4) upfront in regs
// under __launch_bounds__(256,1) (~176 VGPR -> ~12 waves/CU, 36-deep MLP each); reduction
// via wave-synchronous LDS transpose (8 ds_write + 2 ds_read_b128 + 3 shfl + broadcast)
// instead of 48 shfl. Top-2/gates computed redundantly per lane (wave-uniform).
__global__ __launch_bounds__(256, 1) void moe_route(
    const float* __restrict__ x, const float* __restrict__ Wg,
    __bf16* __restrict__ Xb, int* __restrict__ cnt,
    int* __restrict__ ltok,
    int* __restrict__ tsel, float* __restrict__ tgate) {
    __shared__ __align__(16) float red[4][8 * 64];   // per-wave transpose-reduce scratch
    __shared__ __align__(16) float fin[4][8];        // per-wave final logits
    __shared__ int   sE[8];
    __shared__ float sG[8];
    __shared__ int   lcnt[NEXP], lbase[NEXP], lslot[8];
    const int tid  = threadIdx.x;
    const int lane = tid & 63;
    const int wave = tid >> 6;
    const int t = blockIdx.x * 4 + wave;

    const float* xr = x + (size_t)t * H;

    // ---- all loads upfront: 4 x-float4 + 32 Wg-float4, independent, in flight together ----
    float4 xv[4];
#pragma unroll
    for (int c = 0; c < 4; ++c)
        xv[c] = *(const float4*)(xr + c * 256 + lane * 4);
    float4 w[4][8];
#pragma unroll
    for (int c = 0; c < 4; ++c) {
        const float* wgp = Wg + (size_t)(c * 256 + lane * 4) * NEXP;
#pragma unroll
        for (int r = 0; r < 8; ++r) w[c][r] = *(const float4*)(wgp + r * 4);
    }

    // ---- 128 FMAs: a[e] += x[h] * Wg[h][e] over this lane's 16 h's ----
    float a[NEXP];
#pragma unroll
    for (int e = 0; e < NEXP; ++e) a[e] = 0.f;
#pragma unroll
    for (int c = 0; c < 4; ++c) {
        const float xc[4] = {xv[c].x, xv[c].y, xv[c].z, xv[c].w};
#pragma unroll
        for (int i = 0; i < 4; ++i) {
            a[0] += xc[i] * w[c][i * 2].x;     a[1] += xc[i] * w[c][i * 2].y;
            a[2] += xc[i] * w[c][i * 2].z;     a[3] += xc[i] * w[c][i * 2].w;
            a[4] += xc[i] * w[c][i * 2 + 1].x; a[5] += xc[i] * w[c][i * 2 + 1].y;
            a[6] += xc[i] * w[c][i * 2 + 1].z; a[7] += xc[i] * w[c][i * 2 + 1].w;
        }
    }

    // ---- fused bf16 cast of x (fire-and-forget stores) ----
    __bf16* xbr = Xb + (size_t)t * H;
#pragma unroll
    for (int c = 0; c < 4; ++c) {
        bf16x4 xo;
        xo[0] = (__bf16)xv[c].x; xo[1] = (__bf16)xv[c].y;
        xo[2] = (__bf16)xv[c].z; xo[3] = (__bf16)xv[c].w;
        *(bf16x4*)(xbr + c * 256 + lane * 4) = xo;
    }

    // ---- wave-synchronous LDS transpose-reduce (no cross-wave sharing -> no barrier) ----
    // write: bank = lane%32 -> 2-way alias only (free). read: lane sums 8 partials of its
    // expert eL=lane>>3 via 2 ds_read_b128, then 3 shfl_xor across the 8-lane group.
    float* rw = &red[wave][0];
#pragma unroll
    for (int e = 0; e < NEXP; ++e) rw[e * 64 + lane] = a[e];
    const int eL = lane >> 3, l8 = lane & 7;
    const float4 p0 = *(const float4*)&rw[eL * 64 + l8 * 8];
    const float4 p1 = *(const float4*)&rw[eL * 64 + l8 * 8 + 4];
    float s = ((p0.x + p0.y) + (p0.z + p0.w)) + ((p1.x + p1.y) + (p1.z + p1.w));
    s += __shfl_xor(s, 1, 64);
    s += __shfl_xor(s, 2, 64);
    s += __shfl_xor(s, 4, 64);
    if (l8 == 0) fin[wave][eL] = s;
    const float4 f0 = *(const float4*)&fin[wave][0];
    const float4 f1 = *(const float4*)&fin[wave][4];
    const float av[NEXP] = {f0.x, f0.y, f0.z, f0.w, f1.x, f1.y, f1.z, f1.w};

    // ---- top-2 + gates (computed redundantly by all lanes; wave-uniform) ----
    int i0 = 0;
#pragma unroll
    for (int e = 1; e < NEXP; ++e) if (av[e] > av[i0]) i0 = e;   // jax tie-break: lowest idx
    int i1 = (i0 == 0) ? 1 : 0;
#pragma unroll
    for (int e = 0; e < NEXP; ++e) if (e != i0 && av[e] > av[i1]) i1 = e;
    const float ex = __expf(av[i1] - av[i0]);
    const float g0 = 1.f / (1.f + ex);
    const float g1 = ex / (1.f + ex);
    if (lane == 0) {
        sE[wave * 2] = i0; sE[wave * 2 + 1] = i1;
        sG[wave * 2] = g0; sG[wave * 2 + 1] = g1;
    }
    if (tid < NEXP) lcnt[tid] = 0;
    __syncthreads();
    if (tid < 8) lslot[tid] = atomicAdd(&lcnt[sE[tid]], 1);
    __syncthreads();
    if (tid < NEXP) lbase[tid] = lcnt[tid] ? atomicAdd(&cnt[tid * CNTSTRIDE], lcnt[tid]) : 0;
    __syncthreads();
    if (tid < 8) {
        const int e = sE[tid];
        const int sl = lbase[e] + lslot[tid];
        const int tt2 = blockIdx.x * 4 + (tid >> 1);
        ltok[e * CAP + sl] = tt2;
        tsel[tt2 * 2 + (tid & 1)]  = e * CAP + sl;
        tgate[tt2 * 2 + (tid & 1)] = sG[tid];
    }
}

// ---------------- grouped GEMM: 128x128 tile, BK=64 (two BK=32 panels), bf16 MFMA ----------------
// R6/R10 structure (proven ~55us / ~620 TF): 33KB LDS -> ~4 blocks/CU; inter-block overlap
// (m114) beats both the 1-block/CU hand pipeline (R7, 78us) and the atomic fused-combine
// epilogue (R11, 91us). XCD-pinned swizzle: blockIdx&7 = expert (L2-resident B-panel).
__global__ __launch_bounds__(256) void moe_gemm(
    const __bf16* __restrict__ Xb, const __bf16* __restrict__ WeT,
    const float* __restrict__ be, const int* __restrict__ cnt,
    const int* __restrict__ ltok,
    __bf16* __restrict__ Eout) {
    const int e  = blockIdx.x & 7;
    const int nt = (blockIdx.x >> 3) & 7;
    const int mt = blockIdx.x >> 6;
    const int ne = cnt[e * CNTSTRIDE];
    const int m0 = mt * TM;
    if (m0 >= ne) return;
    const int n0 = nt * TN;
    int off = 0;
    for (int i2 = 0; i2 < e; ++i2) off += cnt[i2 * CNTSTRIDE];

    __shared__ __align__(16) __bf16 smem[4 * 4096];  // Al|Al2|Bl|Bl2; epilogue: 4 x (64x64)
    __bf16* Al  = smem;
    __bf16* Al2 = smem + 4096;
    __bf16* Bl  = smem + 8192;
    __bf16* Bl2 = smem + 12288;
    __shared__ int tokL[TM];

    const int tid = threadIdx.x;
    const int lane = tid & 63;
    const int wave = tid >> 6;

    if (tid < TM) {
        const int gi = m0 + tid;
        tokL[tid] = (gi < ne) ? ltok[e * CAP + gi] : 0;
    }
    __syncthreads();

    const __bf16* Bt = WeT + ((size_t)e << 20);
    const int qr = lane >> 4;
    const int rr = lane & 15;
    const int wr = (wave >> 1) * 64;
    const int wc = (wave & 1) * 64;

    f32x4 acc[4][4];
    const f32x4 z = {0.f, 0.f, 0.f, 0.f};
#pragma unroll
    for (int i = 0; i < 4; ++i)
#pragma unroll
        for (int j = 0; j < 4; ++j) acc[i][j] = z;

    const int c0 = tid, c1 = tid + 256;
    const int ar0 = c0 >> 2, ak0 = (((c0 & 3) ^ ((c0 >> 3) & 3)) * 8);
    const int ar1 = c1 >> 2, ak1 = (((c1 & 3) ^ ((c1 >> 3) & 3)) * 8);
    const size_t arow0 = (size_t)tokL[ar0] * H;
    const size_t arow1 = (size_t)tokL[ar1] * H;
    const size_t brow0 = (size_t)(n0 + ar0) * H;
    const size_t brow1 = (size_t)(n0 + ar1) * H;

    for (int k0 = 0; k0 < H; k0 += 64) {
        async16(&Al [c0 * 8], Xb + arow0 + k0 + ak0);
        async16(&Al [c1 * 8], Xb + arow1 + k0 + ak1);
        async16(&Al2[c0 * 8], Xb + arow0 + k0 + 32 + ak0);
        async16(&Al2[c1 * 8], Xb + arow1 + k0 + 32 + ak1);
        async16(&Bl [c0 * 8], Bt + brow0 + k0 + ak0);
        async16(&Bl [c1 * 8], Bt + brow1 + k0 + ak1);
        async16(&Bl2[c0 * 8], Bt + brow0 + k0 + 32 + ak0);
        async16(&Bl2[c1 * 8], Bt + brow1 + k0 + 32 + ak1);
        __syncthreads();
        {
            bf16x8 af[4], bfr[4];
#pragma unroll
            for (int i = 0; i < 4; ++i) {
                const int ra = wr + i * 16 + rr;
                af[i] = *(const bf16x8*)&Al[ra * 32 + ((qr ^ ((ra >> 1) & 3)) * 8)];
            }
#pragma unroll
            for (int j = 0; j < 4; ++j) {
                const int rb = wc + j * 16 + rr;
                bfr[j] = *(const bf16x8*)&Bl[rb * 32 + ((qr ^ ((rb >> 1) & 3)) * 8)];
            }
#pragma unroll
            for (int i = 0; i < 4; ++i)
#pragma unroll
                for (int j = 0; j < 4; ++j)
                    acc[i][j] = __builtin_amdgcn_mfma_f32_16x16x32_bf16(af[i], bfr[j], acc[i][j], 0, 0, 0);
        }
        {
            bf16x8 af[4], bfr[4];
#pragma unroll
            for (int i = 0; i < 4; ++i) {
                const int ra = wr + i * 16 + rr;
                af[i] = *(const bf16x8*)&Al2[ra * 32 + ((qr ^ ((ra >> 1) & 3)) * 8)];
            }
#pragma unroll
            for (int j = 0; j < 4; ++j) {
                const int rb = wc + j * 16 + rr;
                bfr[j] = *(const bf16x8*)&Bl2[rb * 32 + ((qr ^ ((rb >> 1) & 3)) * 8)];
            }
#pragma unroll
            for (int i = 0; i < 4; ++i)
#pragma unroll
                for (int j = 0; j < 4; ++j)
                    acc[i][j] = __builtin_amdgcn_mfma_f32_16x16x32_bf16(af[i], bfr[j], acc[i][j], 0, 0, 0);
        }
        __syncthreads();   // also protects smem reuse by the epilogue on the last iter
    }

    float bev[4];
#pragma unroll
    for (int j = 0; j < 4; ++j) bev[j] = be[e * H + n0 + wc + j * 16 + rr];

    // ---- epilogue: per-wave 64x64 LDS stage (XOR col swizzle), then full-line bf16x8 stores ----
    __bf16* Cw = smem + wave * 4096;
#pragma unroll
    for (int i = 0; i < 4; ++i) {
#pragma unroll
        for (int reg = 0; reg < 4; ++reg) {
            const int row = i * 16 + qr * 4 + reg;      // C/D layout: col=lane&15, row=quad*4+reg
            const int key = (row & 7) * 8;
#pragma unroll
            for (int j = 0; j < 4; ++j) {
                const int c = j * 16 + rr;
                Cw[row * 64 + (c ^ key)] = (__bf16)(acc[i][j][reg] + bev[j]);
            }
        }
    }
    const int lrr = lane & 7, lrg = lane >> 3;
#pragma unroll
    for (int p = 0; p < 8; ++p) {
        const int row = p * 8 + lrg;
        const int rglob = m0 + wr + row;
        if (rglob < ne) {
            const int idx8 = ((lrr ^ (row & 7)) * 8);
            const bf16x8 v = *(const bf16x8*)&Cw[row * 64 + idx8];
            *(bf16x8*)(Eout + (size_t)(off + rglob) * H + n0 + wc + lrr * 8) = v;
        }
    }
}

// ---------------- combine: wave per token, out[t] = g0*row0 + g1*row1 (~12us, near roofline) ----
__global__ __launch_bounds__(256) void moe_combine(
    const __bf16* __restrict__ Eout, const int* __restrict__ cnt,
    const int* __restrict__ tsel, const float* __restrict__ tgate,
    float* __restrict__ out) {
    __shared__ int offs[NEXP];
    if (threadIdx.x < NEXP) {
        int o = 0;
        for (int i = 0; i < (int)threadIdx.x; ++i) o += cnt[i * CNTSTRIDE];
        offs[threadIdx.x] = o;
    }
    __syncthreads();
    const int wave = threadIdx.x >> 6, lane = threadIdx.x & 63;
    const int t = blockIdx.x * 4 + wave;
    const int sel0 = tsel[t * 2],  sel1 = tsel[t * 2 + 1];
    const float g0 = tgate[t * 2], g1  = tgate[t * 2 + 1];
    const int e0 = sel0 >> 13, s0 = sel0 & (CAP - 1);
    const int e1 = sel1 >> 13, s1 = sel1 & (CAP - 1);
    const __bf16* r0 = Eout + (size_t)(offs[e0] + s0) * H;
    const __bf16* r1 = Eout + (size_t)(offs[e1] + s1) * H;
    float* orow = out + (size_t)t * H;
#pragma unroll
    for (int c = 0; c < 2; ++c) {
        const int d = c * 512 + lane * 8;
        const bf16x8 a = *(const bf16x8*)(r0 + d);
        const bf16x8 b = *(const bf16x8*)(r1 + d);
        float4 o0, o1;
        o0.x = g0 * (float)a[0] + g1 * (float)b[0];
        o0.y = g0 * (float)a[1] + g1 * (float)b[1];
        o0.z = g0 * (float)a[2] + g1 * (float)b[2];
        o0.w = g0 * (float)a[3] + g1 * (float)b[3];
        o1.x = g0 * (float)a[4] + g1 * (float)b[4];
        o1.y = g0 * (float)a[5] + g1 * (float)b[5];
        o1.z = g0 * (float)a[6] + g1 * (float)b[6];
        o1.w = g0 * (float)a[7] + g1 * (float)b[7];
        *(float4*)(orow + d)     = o0;
        *(float4*)(orow + d + 4) = o1;
    }
}

extern "C" void kernel_launch(void* const* d_in, const int* in_sizes, int n_in,
                              void* d_out, int out_size, void* d_ws, size_t ws_size,
                              hipStream_t stream) {
    const float* x  = (const float*)d_in[0];
    const float* Wg = (const float*)d_in[1];
    const float* We = (const float*)d_in[2];
    const float* be = (const float*)d_in[3];
    float* out = (float*)d_out;

    char* ws = (char*)d_ws;
    __bf16* Xb   = (__bf16*)ws;
    __bf16* WeT  = (__bf16*)(ws + ((size_t)16 << 20));
    __bf16* Eout = (__bf16*)(ws + ((size_t)32 << 20));
    char*   meta = ws + ((size_t)64 << 20);
    int*    cnt  = (int*)meta;
    int*    ltok = (int*)(meta + 1024);
    int*    tsel = (int*)(meta + 1024 + (size_t)NEXP * CAP * 8);
    float*  tgat = (float*)(meta + 1024 + (size_t)NEXP * CAP * 8 + (size_t)T_TOK * 8);

    moe_transpose<<<2048, 256, 0, stream>>>(We, WeT, cnt);
    moe_route<<<2048, 256, 0, stream>>>(x, Wg, Xb, cnt, ltok, tsel, tgat);
    moe_gemm<<<8 * 8 * (T_TOK / TM), 256, 0, stream>>>(Xb, WeT, be, cnt, ltok, Eout);
    moe_combine<<<T_TOK / 4, 256, 0, stream>>>(Eout, cnt, tsel, tgat, out);
}

// Round 8
// 187.713 us; speedup vs baseline: 1.2336x; 1.1238x over previous
//
#include <hip/hip_runtime.h>
#include <hip/hip_bf16.h>

// Problem constants: B=4,S=2048 -> T=8192 tokens, H=1024, E=8, TOP_K=2
#define H 1024
#define NEXP 8
#define T_TOK 8192
#define CAP 8192
#define TM 128
#define TN 128
#define CNTSTRIDE 32

typedef __bf16 bf16x8 __attribute__((ext_vector_type(8)));
typedef __bf16 bf16x4 __attribute__((ext_vector_type(4)));
typedef float f32x4 __attribute__((ext_vector_type(4)));

__device__ __forceinline__ void async16(void* lds, const void* g) {
    __builtin_amdgcn_global_load_lds(
        (const __attribute__((address_space(1))) void*)g,
        (__attribute__((address_space(3))) void*)lds, 16, 0, 0);
}

// ---------------- transpose: We (E,h,d) fp32 -> WeT (E,d,h) bf16, 64x64 tiles ----------------
// Block 0 also zeroes cnt (replaces the hipMemsetAsync dispatch; transpose fully precedes
// route by stream order, so route's atomics always see zeroed counters).
__global__ __launch_bounds__(256) void moe_transpose(
    const float* __restrict__ We, __bf16* __restrict__ WeT, int* __restrict__ cnt) {
    __shared__ __align__(16) float t[64][65];   // stride 65: 2-way alias only (free, m136)
    const int tid = threadIdx.x;
    if (blockIdx.x == 0 && tid < NEXP) cnt[tid * CNTSTRIDE] = 0;
    const int tt = blockIdx.x;
    const int e  = tt >> 8;
    const int d0 = ((tt >> 4) & 15) * 64;
    const int h0 = (tt & 15) * 64;
    const int tx = tid & 15;
    const int ty = tid >> 4;
    const float* src = We + ((size_t)e << 20);
    __bf16* dst = WeT + ((size_t)e << 20);
#pragma unroll
    for (int p = 0; p < 4; ++p) {
        const int row = p * 16 + ty;
        const float4 v = *(const float4*)(src + (size_t)(h0 + row) * H + d0 + tx * 4);
        t[row][tx * 4 + 0] = v.x; t[row][tx * 4 + 1] = v.y;
        t[row][tx * 4 + 2] = v.z; t[row][tx * 4 + 3] = v.w;
    }
    __syncthreads();
    // 512 bf16x8 chunks (drow, seg), 2/thread. LDS bank check: word = (seg*8+i)*65+drow;
    // across 64 lanes -> 2-way alias only.
#pragma unroll
    for (int qq = 0; qq < 2; ++qq) {
        const int q = tid + qq * 256;
        const int drow = q >> 3;
        const int seg  = q & 7;
        bf16x8 o;
#pragma unroll
        for (int i = 0; i < 8; ++i) o[i] = (__bf16)t[seg * 8 + i][drow];
        *(bf16x8*)(dst + (size_t)(d0 + drow) * H + h0 + seg * 8) = o;
    }
}

// ---------------- route: logits, top-2, gates, compaction; fused x -> bf16 cast -------------
// R14: the constant ~58us across R10/R12/R13 was the Wg GATHER: per float4 instr the 64
// lanes hit 64 distinct 128B-strided cache lines (16.7M line transactions total, TA-bound,
// ~27us/CU floor + latency). Fix: stage Wg TRANSPOSED in LDS once per block (coalesced
// global read, 32KB, L2-broadcast), then read wgT[e][c*256+lane*4] = contiguous 1KB/instr
// conflict-free ds_read_b128. VGPR=36 evidence also showed "upfront reg loads" get sunk by
// the compiler (single-use values) - LDS staging is the schedule-proof form.
__global__ __launch_bounds__(256) void moe_route(
    const float* __restrict__ x, const float* __restrict__ Wg,
    __bf16* __restrict__ Xb, int* __restrict__ cnt,
    int* __restrict__ ltok,
    int* __restrict__ tsel, float* __restrict__ tgate) {
    __shared__ __align__(16) float wgT[NEXP][H];     // 32KB: Wg transposed [e][h]
    __shared__ __align__(16) float red[4][8 * 64];   // per-wave transpose-reduce scratch
    __shared__ __align__(16) float fin[4][8];        // per-wave final logits
    __shared__ int   sE[8];
    __shared__ float sG[8];
    __shared__ int   lcnt[NEXP], lbase[NEXP], lslot[8];
    const int tid  = threadIdx.x;
    const int lane = tid & 63;
    const int wave = tid >> 6;
    const int t = blockIdx.x * 4 + wave;

    // ---- stage Wg -> wgT (coalesced float4 reads; scalar ds_writes, 2-way max) ----
#pragma unroll
    for (int k = 0; k < 8; ++k) {
        const int q = k * 256 + tid;          // q in [0,2048): float4 index into Wg
        const float4 f = ((const float4*)Wg)[q];
        const int h  = q >> 1;
        const int e0 = (q & 1) * 4;
        wgT[e0 + 0][h] = f.x; wgT[e0 + 1][h] = f.y;
        wgT[e0 + 2][h] = f.z; wgT[e0 + 3][h] = f.w;
    }

    // ---- x loads (coalesced, 16B/lane) ----
    const float* xr = x + (size_t)t * H;
    float4 xv[4];
#pragma unroll
    for (int c = 0; c < 4; ++c)
        xv[c] = *(const float4*)(xr + c * 256 + lane * 4);

    // ---- fused bf16 cast of x (fire-and-forget stores) ----
    __bf16* xbr = Xb + (size_t)t * H;
#pragma unroll
    for (int c = 0; c < 4; ++c) {
        bf16x4 xo;
        xo[0] = (__bf16)xv[c].x; xo[1] = (__bf16)xv[c].y;
        xo[2] = (__bf16)xv[c].z; xo[3] = (__bf16)xv[c].w;
        *(bf16x4*)(xbr + c * 256 + lane * 4) = xo;
    }

    __syncthreads();   // wgT ready

    // ---- logits: 32 conflict-free ds_read_b128 + 128 FMA per wave ----
    float a[NEXP];
#pragma unroll
    for (int e = 0; e < NEXP; ++e) a[e] = 0.f;
#pragma unroll
    for (int e = 0; e < NEXP; ++e) {
#pragma unroll
        for (int c = 0; c < 4; ++c) {
            const float4 wv = *(const float4*)&wgT[e][c * 256 + lane * 4];
            a[e] += xv[c].x * wv.x + xv[c].y * wv.y + xv[c].z * wv.z + xv[c].w * wv.w;
        }
    }

    // ---- wave-synchronous LDS transpose-reduce (R13) ----
    float* rw = &red[wave][0];
#pragma unroll
    for (int e = 0; e < NEXP; ++e) rw[e * 64 + lane] = a[e];
    const int eL = lane >> 3, l8 = lane & 7;
    const float4 p0 = *(const float4*)&rw[eL * 64 + l8 * 8];
    const float4 p1 = *(const float4*)&rw[eL * 64 + l8 * 8 + 4];
    float s = ((p0.x + p0.y) + (p0.z + p0.w)) + ((p1.x + p1.y) + (p1.z + p1.w));
    s += __shfl_xor(s, 1, 64);
    s += __shfl_xor(s, 2, 64);
    s += __shfl_xor(s, 4, 64);
    if (l8 == 0) fin[wave][eL] = s;
    const float4 f0 = *(const float4*)&fin[wave][0];
    const float4 f1 = *(const float4*)&fin[wave][4];
    const float av[NEXP] = {f0.x, f0.y, f0.z, f0.w, f1.x, f1.y, f1.z, f1.w};

    // ---- top-2 + gates (computed redundantly by all lanes; wave-uniform) ----
    int i0 = 0;
#pragma unroll
    for (int e = 1; e < NEXP; ++e) if (av[e] > av[i0]) i0 = e;   // jax tie-break: lowest idx
    int i1 = (i0 == 0) ? 1 : 0;
#pragma unroll
    for (int e = 0; e < NEXP; ++e) if (e != i0 && av[e] > av[i1]) i1 = e;
    const float ex = __expf(av[i1] - av[i0]);
    const float g0 = 1.f / (1.f + ex);
    const float g1 = ex / (1.f + ex);
    if (lane == 0) {
        sE[wave * 2] = i0; sE[wave * 2 + 1] = i1;
        sG[wave * 2] = g0; sG[wave * 2 + 1] = g1;
    }
    if (tid < NEXP) lcnt[tid] = 0;
    __syncthreads();
    if (tid < 8) lslot[tid] = atomicAdd(&lcnt[sE[tid]], 1);
    __syncthreads();
    if (tid < NEXP) lbase[tid] = lcnt[tid] ? atomicAdd(&cnt[tid * CNTSTRIDE], lcnt[tid]) : 0;
    __syncthreads();
    if (tid < 8) {
        const int e = sE[tid];
        const int sl = lbase[e] + lslot[tid];
        const int tt2 = blockIdx.x * 4 + (tid >> 1);
        ltok[e * CAP + sl] = tt2;
        tsel[tt2 * 2 + (tid & 1)]  = e * CAP + sl;
        tgate[tt2 * 2 + (tid & 1)] = sG[tid];
    }
}

// ---------------- grouped GEMM: 128x128 tile, BK=64 (two BK=32 panels), bf16 MFMA ----------------
// R6/R10 structure (proven ~55us / ~620 TF): 33KB LDS -> ~4 blocks/CU; inter-block overlap
// (m114) beats both the 1-block/CU hand pipeline (R7, 78us) and the atomic fused-combine
// epilogue (R11, 91us). XCD-pinned swizzle: blockIdx&7 = expert (L2-resident B-panel).
__global__ __launch_bounds__(256) void moe_gemm(
    const __bf16* __restrict__ Xb, const __bf16* __restrict__ WeT,
    const float* __restrict__ be, const int* __restrict__ cnt,
    const int* __restrict__ ltok,
    __bf16* __restrict__ Eout) {
    const int e  = blockIdx.x & 7;
    const int nt = (blockIdx.x >> 3) & 7;
    const int mt = blockIdx.x >> 6;
    const int ne = cnt[e * CNTSTRIDE];
    const int m0 = mt * TM;
    if (m0 >= ne) return;
    const int n0 = nt * TN;
    int off = 0;
    for (int i2 = 0; i2 < e; ++i2) off += cnt[i2 * CNTSTRIDE];

    __shared__ __align__(16) __bf16 smem[4 * 4096];  // Al|Al2|Bl|Bl2; epilogue: 4 x (64x64)
    __bf16* Al  = smem;
    __bf16* Al2 = smem + 4096;
    __bf16* Bl  = smem + 8192;
    __bf16* Bl2 = smem + 12288;
    __shared__ int tokL[TM];

    const int tid = threadIdx.x;
    const int lane = tid & 63;
    const int wave = tid >> 6;

    if (tid < TM) {
        const int gi = m0 + tid;
        tokL[tid] = (gi < ne) ? ltok[e * CAP + gi] : 0;
    }
    __syncthreads();

    const __bf16* Bt = WeT + ((size_t)e << 20);
    const int qr = lane >> 4;
    const int rr = lane & 15;
    const int wr = (wave >> 1) * 64;
    const int wc = (wave & 1) * 64;

    f32x4 acc[4][4];
    const f32x4 z = {0.f, 0.f, 0.f, 0.f};
#pragma unroll
    for (int i = 0; i < 4; ++i)
#pragma unroll
        for (int j = 0; j < 4; ++j) acc[i][j] = z;

    const int c0 = tid, c1 = tid + 256;
    const int ar0 = c0 >> 2, ak0 = (((c0 & 3) ^ ((c0 >> 3) & 3)) * 8);
    const int ar1 = c1 >> 2, ak1 = (((c1 & 3) ^ ((c1 >> 3) & 3)) * 8);
    const size_t arow0 = (size_t)tokL[ar0] * H;
    const size_t arow1 = (size_t)tokL[ar1] * H;
    const size_t brow0 = (size_t)(n0 + ar0) * H;
    const size_t brow1 = (size_t)(n0 + ar1) * H;

    for (int k0 = 0; k0 < H; k0 += 64) {
        async16(&Al [c0 * 8], Xb + arow0 + k0 + ak0);
        async16(&Al [c1 * 8], Xb + arow1 + k0 + ak1);
        async16(&Al2[c0 * 8], Xb + arow0 + k0 + 32 + ak0);
        async16(&Al2[c1 * 8], Xb + arow1 + k0 + 32 + ak1);
        async16(&Bl [c0 * 8], Bt + brow0 + k0 + ak0);
        async16(&Bl [c1 * 8], Bt + brow1 + k0 + ak1);
        async16(&Bl2[c0 * 8], Bt + brow0 + k0 + 32 + ak0);
        async16(&Bl2[c1 * 8], Bt + brow1 + k0 + 32 + ak1);
        __syncthreads();
        {
            bf16x8 af[4], bfr[4];
#pragma unroll
            for (int i = 0; i < 4; ++i) {
                const int ra = wr + i * 16 + rr;
                af[i] = *(const bf16x8*)&Al[ra * 32 + ((qr ^ ((ra >> 1) & 3)) * 8)];
            }
#pragma unroll
            for (int j = 0; j < 4; ++j) {
                const int rb = wc + j * 16 + rr;
                bfr[j] = *(const bf16x8*)&Bl[rb * 32 + ((qr ^ ((rb >> 1) & 3)) * 8)];
            }
#pragma unroll
            for (int i = 0; i < 4; ++i)
#pragma unroll
                for (int j = 0; j < 4; ++j)
                    acc[i][j] = __builtin_amdgcn_mfma_f32_16x16x32_bf16(af[i], bfr[j], acc[i][j], 0, 0, 0);
        }
        {
            bf16x8 af[4], bfr[4];
#pragma unroll
            for (int i = 0; i < 4; ++i) {
                const int ra = wr + i * 16 + rr;
                af[i] = *(const bf16x8*)&Al2[ra * 32 + ((qr ^ ((ra >> 1) & 3)) * 8)];
            }
#pragma unroll
            for (int j = 0; j < 4; ++j) {
                const int rb = wc + j * 16 + rr;
                bfr[j] = *(const bf16x8*)&Bl2[rb * 32 + ((qr ^ ((rb >> 1) & 3)) * 8)];
            }
#pragma unroll
            for (int i = 0; i < 4; ++i)
#pragma unroll
                for (int j = 0; j < 4; ++j)
                    acc[i][j] = __builtin_amdgcn_mfma_f32_16x16x32_bf16(af[i], bfr[j], acc[i][j], 0, 0, 0);
        }
        __syncthreads();   // also protects smem reuse by the epilogue on the last iter
    }

    float bev[4];
#pragma unroll
    for (int j = 0; j < 4; ++j) bev[j] = be[e * H + n0 + wc + j * 16 + rr];

    // ---- epilogue: per-wave 64x64 LDS stage (XOR col swizzle), then full-line bf16x8 stores ----
    __bf16* Cw = smem + wave * 4096;
#pragma unroll
    for (int i = 0; i < 4; ++i) {
#pragma unroll
        for (int reg = 0; reg < 4; ++reg) {
            const int row = i * 16 + qr * 4 + reg;      // C/D layout: col=lane&15, row=quad*4+reg
            const int key = (row & 7) * 8;
#pragma unroll
            for (int j = 0; j < 4; ++j) {
                const int c = j * 16 + rr;
                Cw[row * 64 + (c ^ key)] = (__bf16)(acc[i][j][reg] + bev[j]);
            }
        }
    }
    const int lrr = lane & 7, lrg = lane >> 3;
#pragma unroll
    for (int p = 0; p < 8; ++p) {
        const int row = p * 8 + lrg;
        const int rglob = m0 + wr + row;
        if (rglob < ne) {
            const int idx8 = ((lrr ^ (row & 7)) * 8);
            const bf16x8 v = *(const bf16x8*)&Cw[row * 64 + idx8];
            *(bf16x8*)(Eout + (size_t)(off + rglob) * H + n0 + wc + lrr * 8) = v;
        }
    }
}

// ---------------- combine: wave per token, out[t] = g0*row0 + g1*row1 (~12us, near roofline) ----
__global__ __launch_bounds__(256) void moe_combine(
    const __bf16* __restrict__ Eout, const int* __restrict__ cnt,
    const int* __restrict__ tsel, const float* __restrict__ tgate,
    float* __restrict__ out) {
    __shared__ int offs[NEXP];
    if (threadIdx.x < NEXP) {
        int o = 0;
        for (int i = 0; i < (int)threadIdx.x; ++i) o += cnt[i * CNTSTRIDE];
        offs[threadIdx.x] = o;
    }
    __syncthreads();
    const int wave = threadIdx.x >> 6, lane = threadIdx.x & 63;
    const int t = blockIdx.x * 4 + wave;
    const int sel0 = tsel[t * 2],  sel1 = tsel[t * 2 + 1];
    const float g0 = tgate[t * 2], g1  = tgate[t * 2 + 1];
    const int e0 = sel0 >> 13, s0 = sel0 & (CAP - 1);
    const int e1 = sel1 >> 13, s1 = sel1 & (CAP - 1);
    const __bf16* r0 = Eout + (size_t)(offs[e0] + s0) * H;
    const __bf16* r1 = Eout + (size_t)(offs[e1] + s1) * H;
    float* orow = out + (size_t)t * H;
#pragma unroll
    for (int c = 0; c < 2; ++c) {
        const int d = c * 512 + lane * 8;
        const bf16x8 a = *(const bf16x8*)(r0 + d);
        const bf16x8 b = *(const bf16x8*)(r1 + d);
        float4 o0, o1;
        o0.x = g0 * (float)a[0] + g1 * (float)b[0];
        o0.y = g0 * (float)a[1] + g1 * (float)b[1];
        o0.z = g0 * (float)a[2] + g1 * (float)b[2];
        o0.w = g0 * (float)a[3] + g1 * (float)b[3];
        o1.x = g0 * (float)a[4] + g1 * (float)b[4];
        o1.y = g0 * (float)a[5] + g1 * (float)b[5];
        o1.z = g0 * (float)a[6] + g1 * (float)b[6];
        o1.w = g0 * (float)a[7] + g1 * (float)b[7];
        *(float4*)(orow + d)     = o0;
        *(float4*)(orow + d + 4) = o1;
    }
}

extern "C" void kernel_launch(void* const* d_in, const int* in_sizes, int n_in,
                              void* d_out, int out_size, void* d_ws, size_t ws_size,
                              hipStream_t stream) {
    const float* x  = (const float*)d_in[0];
    const float* Wg = (const float*)d_in[1];
    const float* We = (const float*)d_in[2];
    const float* be = (const float*)d_in[3];
    float* out = (float*)d_out;

    char* ws = (char*)d_ws;
    __bf16* Xb   = (__bf16*)ws;
    __bf16* WeT  = (__bf16*)(ws + ((size_t)16 << 20));
    __bf16* Eout = (__bf16*)(ws + ((size_t)32 << 20));
    char*   meta = ws + ((size_t)64 << 20);
    int*    cnt  = (int*)meta;
    int*    ltok = (int*)(meta + 1024);
    int*    tsel = (int*)(meta + 1024 + (size_t)NEXP * CAP * 8);
    float*  tgat = (float*)(meta + 1024 + (size_t)NEXP * CAP * 8 + (size_t)T_TOK * 8);

    moe_transpose<<<2048, 256, 0, stream>>>(We, WeT, cnt);
    moe_route<<<2048, 256, 0, stream>>>(x, Wg, Xb, cnt, ltok, tsel, tgat);
    moe_gemm<<<8 * 8 * (T_TOK / TM), 256, 0, stream>>>(Xb, WeT, be, cnt, ltok, Eout);
    moe_combine<<<T_TOK / 4, 256, 0, stream>>>(Eout, cnt, tsel, tgat, out);
}

// Round 9
// 182.150 us; speedup vs baseline: 1.2712x; 1.0305x over previous
//
#include <hip/hip_runtime.h>
#include <hip/hip_bf16.h>

// Problem constants: B=4,S=2048 -> T=8192 tokens, H=1024, E=8, TOP_K=2
#define H 1024
#define NEXP 8
#define T_TOK 8192
#define CAP 8192
#define TM 128
#define TN 128
#define CNTSTRIDE 32

typedef __bf16 bf16x8 __attribute__((ext_vector_type(8)));
typedef __bf16 bf16x4 __attribute__((ext_vector_type(4)));
typedef float f32x4 __attribute__((ext_vector_type(4)));

__device__ __forceinline__ void async16(void* lds, const void* g) {
    __builtin_amdgcn_global_load_lds(
        (const __attribute__((address_space(1))) void*)g,
        (__attribute__((address_space(3))) void*)lds, 16, 0, 0);
}

// ---------------- prep: route (blocks 0..2047) + We-transpose (blocks 2048..4095) -----------
// R15: fused as BLOCK RANGES of one dispatch (not R9's 1:1 interleave, whose real defect was
// the Wg gather, fixed in R14). The two streams are independent; fusing removes one launch
// boundary and overlaps route's LDS-heavy phase with transpose's memory phase.
// LDS union: route wgT (32KB, reused as reduce scratch behind a barrier) vs transpose tile
// (16.6KB) -> 33KB/block. cnt zeroing moved to a memset (intra-kernel block order undefined).
__global__ __launch_bounds__(256) void moe_prep(
    const float* __restrict__ We, __bf16* __restrict__ WeT,
    const float* __restrict__ x, const float* __restrict__ Wg,
    __bf16* __restrict__ Xb, int* __restrict__ cnt,
    int* __restrict__ ltok,
    int* __restrict__ tsel, float* __restrict__ tgate) {
    __shared__ __align__(16) char smem[NEXP * H * 4];   // 32KB: wgT | red (aliased) | transpose tile
    __shared__ __align__(16) float fin[4][8];
    __shared__ int   sE[8];
    __shared__ float sG[8];
    __shared__ int   lcnt[NEXP], lbase[NEXP], lslot[8];
    const int tid  = threadIdx.x;
    const int lane = tid & 63;
    const int wave = tid >> 6;

    if (blockIdx.x >= 2048) {
        // ---- transpose: We (E,h,d) fp32 -> WeT (E,d,h) bf16, 64x64 tile ----
        float (*t)[65] = (float(*)[65])smem;   // 16.6KB; stride 65: 2-way alias only
        const int tt = blockIdx.x - 2048;
        const int e  = tt >> 8;
        const int d0 = ((tt >> 4) & 15) * 64;
        const int h0 = (tt & 15) * 64;
        const int tx = tid & 15;
        const int ty = tid >> 4;
        const float* src = We + ((size_t)e << 20);
        __bf16* dst = WeT + ((size_t)e << 20);
#pragma unroll
        for (int p = 0; p < 4; ++p) {
            const int row = p * 16 + ty;
            const float4 v = *(const float4*)(src + (size_t)(h0 + row) * H + d0 + tx * 4);
            t[row][tx * 4 + 0] = v.x; t[row][tx * 4 + 1] = v.y;
            t[row][tx * 4 + 2] = v.z; t[row][tx * 4 + 3] = v.w;
        }
        __syncthreads();
        // 512 bf16x8 chunks (drow, seg), 2/thread; LDS word (seg*8+i)*65+drow -> 2-way max.
#pragma unroll
        for (int qq = 0; qq < 2; ++qq) {
            const int q = tid + qq * 256;
            const int drow = q >> 3;
            const int seg  = q & 7;
            bf16x8 o;
#pragma unroll
            for (int i = 0; i < 8; ++i) o[i] = (__bf16)t[seg * 8 + i][drow];
            *(bf16x8*)(dst + (size_t)(d0 + drow) * H + h0 + seg * 8) = o;
        }
        return;
    }

    // ---- route: logits via LDS-staged Wg^T (R14 fix), top-2, gates, compaction ----
    float (*wgT)[H] = (float(*)[H])smem;       // 32KB
    const int t = blockIdx.x * 4 + wave;

    // stage Wg -> wgT (coalesced float4 reads; scalar ds_writes, 2-way max)
#pragma unroll
    for (int k = 0; k < 8; ++k) {
        const int q = k * 256 + tid;           // q in [0,2048): float4 index into Wg
        const float4 f = ((const float4*)Wg)[q];
        const int h  = q >> 1;
        const int e0 = (q & 1) * 4;
        wgT[e0 + 0][h] = f.x; wgT[e0 + 1][h] = f.y;
        wgT[e0 + 2][h] = f.z; wgT[e0 + 3][h] = f.w;
    }

    // x loads (coalesced, 16B/lane)
    const float* xr = x + (size_t)t * H;
    float4 xv[4];
#pragma unroll
    for (int c = 0; c < 4; ++c)
        xv[c] = *(const float4*)(xr + c * 256 + lane * 4);

    // fused bf16 cast of x (fire-and-forget stores)
    __bf16* xbr = Xb + (size_t)t * H;
#pragma unroll
    for (int c = 0; c < 4; ++c) {
        bf16x4 xo;
        xo[0] = (__bf16)xv[c].x; xo[1] = (__bf16)xv[c].y;
        xo[2] = (__bf16)xv[c].z; xo[3] = (__bf16)xv[c].w;
        *(bf16x4*)(xbr + c * 256 + lane * 4) = xo;
    }

    __syncthreads();   // wgT ready

    // logits: 32 conflict-free ds_read_b128 + 128 FMA per wave
    float a[NEXP];
#pragma unroll
    for (int e = 0; e < NEXP; ++e) a[e] = 0.f;
#pragma unroll
    for (int e = 0; e < NEXP; ++e) {
#pragma unroll
        for (int c = 0; c < 4; ++c) {
            const float4 wv = *(const float4*)&wgT[e][c * 256 + lane * 4];
            a[e] += xv[c].x * wv.x + xv[c].y * wv.y + xv[c].z * wv.z + xv[c].w * wv.w;
        }
    }
    if (tid < NEXP) lcnt[tid] = 0;
    __syncthreads();   // all waves done reading wgT -> safe to alias red over it

    // wave-synchronous LDS transpose-reduce (red aliases wgT region)
    float* rw = (float*)smem + wave * 512;
#pragma unroll
    for (int e = 0; e < NEXP; ++e) rw[e * 64 + lane] = a[e];
    const int eL = lane >> 3, l8 = lane & 7;
    const float4 p0 = *(const float4*)&rw[eL * 64 + l8 * 8];
    const float4 p1 = *(const float4*)&rw[eL * 64 + l8 * 8 + 4];
    float s = ((p0.x + p0.y) + (p0.z + p0.w)) + ((p1.x + p1.y) + (p1.z + p1.w));
    s += __shfl_xor(s, 1, 64);
    s += __shfl_xor(s, 2, 64);
    s += __shfl_xor(s, 4, 64);
    if (l8 == 0) fin[wave][eL] = s;
    const float4 f0 = *(const float4*)&fin[wave][0];
    const float4 f1 = *(const float4*)&fin[wave][4];
    const float av[NEXP] = {f0.x, f0.y, f0.z, f0.w, f1.x, f1.y, f1.z, f1.w};

    // top-2 + gates (computed redundantly by all lanes; wave-uniform)
    int i0 = 0;
#pragma unroll
    for (int e = 1; e < NEXP; ++e) if (av[e] > av[i0]) i0 = e;   // jax tie-break: lowest idx
    int i1 = (i0 == 0) ? 1 : 0;
#pragma unroll
    for (int e = 0; e < NEXP; ++e) if (e != i0 && av[e] > av[i1]) i1 = e;
    const float ex = __expf(av[i1] - av[i0]);
    const float g0 = 1.f / (1.f + ex);
    const float g1 = ex / (1.f + ex);
    if (lane == 0) {
        sE[wave * 2] = i0; sE[wave * 2 + 1] = i1;
        sG[wave * 2] = g0; sG[wave * 2 + 1] = g1;
    }
    __syncthreads();
    if (tid < 8) lslot[tid] = atomicAdd(&lcnt[sE[tid]], 1);
    __syncthreads();
    if (tid < NEXP) lbase[tid] = lcnt[tid] ? atomicAdd(&cnt[tid * CNTSTRIDE], lcnt[tid]) : 0;
    __syncthreads();
    if (tid < 8) {
        const int e = sE[tid];
        const int sl = lbase[e] + lslot[tid];
        const int tt2 = blockIdx.x * 4 + (tid >> 1);
        ltok[e * CAP + sl] = tt2;
        tsel[tt2 * 2 + (tid & 1)]  = e * CAP + sl;
        tgate[tt2 * 2 + (tid & 1)] = sG[tid];
    }
}

// ---------------- grouped GEMM: 128x128 tile, BK=64 (two BK=32 panels), bf16 MFMA ----------------
// R6/R10 structure (proven ~55us / ~620 TF): 33KB LDS -> ~4 blocks/CU; inter-block overlap
// (m114) beats both the 1-block/CU hand pipeline (R7, 78us) and the atomic fused-combine
// epilogue (R11, 91us). XCD-pinned swizzle: blockIdx&7 = expert (L2-resident B-panel).
__global__ __launch_bounds__(256) void moe_gemm(
    const __bf16* __restrict__ Xb, const __bf16* __restrict__ WeT,
    const float* __restrict__ be, const int* __restrict__ cnt,
    const int* __restrict__ ltok,
    __bf16* __restrict__ Eout) {
    const int e  = blockIdx.x & 7;
    const int nt = (blockIdx.x >> 3) & 7;
    const int mt = blockIdx.x >> 6;
    const int ne = cnt[e * CNTSTRIDE];
    const int m0 = mt * TM;
    if (m0 >= ne) return;
    const int n0 = nt * TN;
    int off = 0;
    for (int i2 = 0; i2 < e; ++i2) off += cnt[i2 * CNTSTRIDE];

    __shared__ __align__(16) __bf16 smem[4 * 4096];  // Al|Al2|Bl|Bl2; epilogue: 4 x (64x64)
    __bf16* Al  = smem;
    __bf16* Al2 = smem + 4096;
    __bf16* Bl  = smem + 8192;
    __bf16* Bl2 = smem + 12288;
    __shared__ int tokL[TM];

    const int tid = threadIdx.x;
    const int lane = tid & 63;
    const int wave = tid >> 6;

    if (tid < TM) {
        const int gi = m0 + tid;
        tokL[tid] = (gi < ne) ? ltok[e * CAP + gi] : 0;
    }
    __syncthreads();

    const __bf16* Bt = WeT + ((size_t)e << 20);
    const int qr = lane >> 4;
    const int rr = lane & 15;
    const int wr = (wave >> 1) * 64;
    const int wc = (wave & 1) * 64;

    f32x4 acc[4][4];
    const f32x4 z = {0.f, 0.f, 0.f, 0.f};
#pragma unroll
    for (int i = 0; i < 4; ++i)
#pragma unroll
        for (int j = 0; j < 4; ++j) acc[i][j] = z;

    const int c0 = tid, c1 = tid + 256;
    const int ar0 = c0 >> 2, ak0 = (((c0 & 3) ^ ((c0 >> 3) & 3)) * 8);
    const int ar1 = c1 >> 2, ak1 = (((c1 & 3) ^ ((c1 >> 3) & 3)) * 8);
    const size_t arow0 = (size_t)tokL[ar0] * H;
    const size_t arow1 = (size_t)tokL[ar1] * H;
    const size_t brow0 = (size_t)(n0 + ar0) * H;
    const size_t brow1 = (size_t)(n0 + ar1) * H;

    for (int k0 = 0; k0 < H; k0 += 64) {
        async16(&Al [c0 * 8], Xb + arow0 + k0 + ak0);
        async16(&Al [c1 * 8], Xb + arow1 + k0 + ak1);
        async16(&Al2[c0 * 8], Xb + arow0 + k0 + 32 + ak0);
        async16(&Al2[c1 * 8], Xb + arow1 + k0 + 32 + ak1);
        async16(&Bl [c0 * 8], Bt + brow0 + k0 + ak0);
        async16(&Bl [c1 * 8], Bt + brow1 + k0 + ak1);
        async16(&Bl2[c0 * 8], Bt + brow0 + k0 + 32 + ak0);
        async16(&Bl2[c1 * 8], Bt + brow1 + k0 + 32 + ak1);
        __syncthreads();
        {
            bf16x8 af[4], bfr[4];
#pragma unroll
            for (int i = 0; i < 4; ++i) {
                const int ra = wr + i * 16 + rr;
                af[i] = *(const bf16x8*)&Al[ra * 32 + ((qr ^ ((ra >> 1) & 3)) * 8)];
            }
#pragma unroll
            for (int j = 0; j < 4; ++j) {
                const int rb = wc + j * 16 + rr;
                bfr[j] = *(const bf16x8*)&Bl[rb * 32 + ((qr ^ ((rb >> 1) & 3)) * 8)];
            }
#pragma unroll
            for (int i = 0; i < 4; ++i)
#pragma unroll
                for (int j = 0; j < 4; ++j)
                    acc[i][j] = __builtin_amdgcn_mfma_f32_16x16x32_bf16(af[i], bfr[j], acc[i][j], 0, 0, 0);
        }
        {
            bf16x8 af[4], bfr[4];
#pragma unroll
            for (int i = 0; i < 4; ++i) {
                const int ra = wr + i * 16 + rr;
                af[i] = *(const bf16x8*)&Al2[ra * 32 + ((qr ^ ((ra >> 1) & 3)) * 8)];
            }
#pragma unroll
            for (int j = 0; j < 4; ++j) {
                const int rb = wc + j * 16 + rr;
                bfr[j] = *(const bf16x8*)&Bl2[rb * 32 + ((qr ^ ((rb >> 1) & 3)) * 8)];
            }
#pragma unroll
            for (int i = 0; i < 4; ++i)
#pragma unroll
                for (int j = 0; j < 4; ++j)
                    acc[i][j] = __builtin_amdgcn_mfma_f32_16x16x32_bf16(af[i], bfr[j], acc[i][j], 0, 0, 0);
        }
        __syncthreads();   // also protects smem reuse by the epilogue on the last iter
    }

    float bev[4];
#pragma unroll
    for (int j = 0; j < 4; ++j) bev[j] = be[e * H + n0 + wc + j * 16 + rr];

    // ---- epilogue: per-wave 64x64 LDS stage (XOR col swizzle), then full-line bf16x8 stores ----
    __bf16* Cw = smem + wave * 4096;
#pragma unroll
    for (int i = 0; i < 4; ++i) {
#pragma unroll
        for (int reg = 0; reg < 4; ++reg) {
            const int row = i * 16 + qr * 4 + reg;      // C/D layout: col=lane&15, row=quad*4+reg
            const int key = (row & 7) * 8;
#pragma unroll
            for (int j = 0; j < 4; ++j) {
                const int c = j * 16 + rr;
                Cw[row * 64 + (c ^ key)] = (__bf16)(acc[i][j][reg] + bev[j]);
            }
        }
    }
    const int lrr = lane & 7, lrg = lane >> 3;
#pragma unroll
    for (int p = 0; p < 8; ++p) {
        const int row = p * 8 + lrg;
        const int rglob = m0 + wr + row;
        if (rglob < ne) {
            const int idx8 = ((lrr ^ (row & 7)) * 8);
            const bf16x8 v = *(const bf16x8*)&Cw[row * 64 + idx8];
            *(bf16x8*)(Eout + (size_t)(off + rglob) * H + n0 + wc + lrr * 8) = v;
        }
    }
}

// ---------------- combine: wave per token, out[t] = g0*row0 + g1*row1 (~12us, near roofline) ----
__global__ __launch_bounds__(256) void moe_combine(
    const __bf16* __restrict__ Eout, const int* __restrict__ cnt,
    const int* __restrict__ tsel, const float* __restrict__ tgate,
    float* __restrict__ out) {
    __shared__ int offs[NEXP];
    if (threadIdx.x < NEXP) {
        int o = 0;
        for (int i = 0; i < (int)threadIdx.x; ++i) o += cnt[i * CNTSTRIDE];
        offs[threadIdx.x] = o;
    }
    __syncthreads();
    const int wave = threadIdx.x >> 6, lane = threadIdx.x & 63;
    const int t = blockIdx.x * 4 + wave;
    const int sel0 = tsel[t * 2],  sel1 = tsel[t * 2 + 1];
    const float g0 = tgate[t * 2], g1  = tgate[t * 2 + 1];
    const int e0 = sel0 >> 13, s0 = sel0 & (CAP - 1);
    const int e1 = sel1 >> 13, s1 = sel1 & (CAP - 1);
    const __bf16* r0 = Eout + (size_t)(offs[e0] + s0) * H;
    const __bf16* r1 = Eout + (size_t)(offs[e1] + s1) * H;
    float* orow = out + (size_t)t * H;
#pragma unroll
    for (int c = 0; c < 2; ++c) {
        const int d = c * 512 + lane * 8;
        const bf16x8 a = *(const bf16x8*)(r0 + d);
        const bf16x8 b = *(const bf16x8*)(r1 + d);
        float4 o0, o1;
        o0.x = g0 * (float)a[0] + g1 * (float)b[0];
        o0.y = g0 * (float)a[1] + g1 * (float)b[1];
        o0.z = g0 * (float)a[2] + g1 * (float)b[2];
        o0.w = g0 * (float)a[3] + g1 * (float)b[3];
        o1.x = g0 * (float)a[4] + g1 * (float)b[4];
        o1.y = g0 * (float)a[5] + g1 * (float)b[5];
        o1.z = g0 * (float)a[6] + g1 * (float)b[6];
        o1.w = g0 * (float)a[7] + g1 * (float)b[7];
        *(float4*)(orow + d)     = o0;
        *(float4*)(orow + d + 4) = o1;
    }
}

extern "C" void kernel_launch(void* const* d_in, const int* in_sizes, int n_in,
                              void* d_out, int out_size, void* d_ws, size_t ws_size,
                              hipStream_t stream) {
    const float* x  = (const float*)d_in[0];
    const float* Wg = (const float*)d_in[1];
    const float* We = (const float*)d_in[2];
    const float* be = (const float*)d_in[3];
    float* out = (float*)d_out;

    char* ws = (char*)d_ws;
    __bf16* Xb   = (__bf16*)ws;
    __bf16* WeT  = (__bf16*)(ws + ((size_t)16 << 20));
    __bf16* Eout = (__bf16*)(ws + ((size_t)32 << 20));
    char*   meta = ws + ((size_t)64 << 20);
    int*    cnt  = (int*)meta;
    int*    ltok = (int*)(meta + 1024);
    int*    tsel = (int*)(meta + 1024 + (size_t)NEXP * CAP * 8);
    float*  tgat = (float*)(meta + 1024 + (size_t)NEXP * CAP * 8 + (size_t)T_TOK * 8);

    hipMemsetAsync(cnt, 0, NEXP * CNTSTRIDE * sizeof(int), stream);

    moe_prep<<<4096, 256, 0, stream>>>(We, WeT, x, Wg, Xb, cnt, ltok, tsel, tgat);
    moe_gemm<<<8 * 8 * (T_TOK / TM), 256, 0, stream>>>(Xb, WeT, be, cnt, ltok, Eout);
    moe_combine<<<T_TOK / 4, 256, 0, stream>>>(Eout, cnt, tsel, tgat, out);
}